// Round 1
// baseline (62.119 us; speedup 1.0000x reference)
//
#include <hip/hip_runtime.h>

// Problem constants (B=32, S=1024, H=512, D=2H=1024)
#define B 32
#define S 1024
#define D 1024
#define H 512

// Workspace layout (in floats):
//   [0,1024)        u[d]      = sum_e v[e]*Wh_w[e,d]        (atomically accumulated)
//   [1024,2048)     usw[d]    = sum_e v[e]*Ws_w[e,d]        (atomically accumulated)
//   [2048]          c         = sum_e Wc_w[e]*v[e]
//   [2052,2084)     dscore[b] = s_t[b]·usw + v·Ws_b
//   [4096,36864)    score[b*S+s]
//   [36864,561152)  ctx partials: (b,schunk=16,d) float
#define WS_U      0
#define WS_USW    1024
#define WS_C      2048
#define WS_DS     2052
#define WS_SCORE  4096
#define WS_PART   36864

__device__ inline float wave_reduce_sum(float v) {
    #pragma unroll
    for (int off = 32; off > 0; off >>= 1) v += __shfl_xor(v, off, 64);
    return v;
}

// Kernel 1: u[d] and usw[d] via e-split partial dots + atomicAdd.
// grid = 256 blocks: mat(2) x dchunk(4) x echunk(32); block = 256 threads.
__global__ __launch_bounds__(256) void prep_kernel(
    const float* __restrict__ Wh, const float* __restrict__ Ws,
    const float* __restrict__ v, float* __restrict__ ws) {
    int blk = blockIdx.x;
    int mat = blk >> 7;             // 0: Wh -> u, 1: Ws -> usw
    int dchunk = (blk >> 5) & 3;
    int echunk = blk & 31;
    const float* W = mat ? Ws : Wh;
    float* dst = ws + (mat ? WS_USW : WS_U);
    int d = dchunk * 256 + threadIdx.x;
    int e0 = echunk * 32;
    float acc = 0.f;
    #pragma unroll 8
    for (int e = e0; e < e0 + 32; ++e)
        acc += v[e] * W[e * D + d];
    atomicAdd(&dst[d], acc);
}

// Kernel 2: dscore[b] = s_t[b]·usw + v·Ws_b ; block 0 also writes c = Wc·v.
// grid = 32 blocks (one per b), block = 256 threads.
__global__ __launch_bounds__(256) void dscore_kernel(
    const float* __restrict__ h_dec, const float* __restrict__ c_dec,
    const float* __restrict__ Ws_b, const float* __restrict__ Wc,
    const float* __restrict__ v, float* __restrict__ ws) {
    int b = blockIdx.x, tid = threadIdx.x;
    const float* usw = ws + WS_USW;
    float pa = 0.f, pb = 0.f;
    #pragma unroll
    for (int k = 0; k < 4; ++k) {
        int i = tid + k * 256;
        float st = (i < H) ? h_dec[b * H + i] : c_dec[b * H + (i - H)];
        pa += st * usw[i];
        pa += v[i] * Ws_b[i];
        pb += v[i] * Wc[i];
    }
    __shared__ float redx[256];
    __shared__ float redy[256];
    redx[tid] = pa; redy[tid] = pb;
    __syncthreads();
    for (int s = 128; s > 0; s >>= 1) {
        if (tid < s) { redx[tid] += redx[tid + s]; redy[tid] += redy[tid + s]; }
        __syncthreads();
    }
    if (tid == 0) {
        ws[WS_DS + b] = redx[0];
        if (b == 0) ws[WS_C] = redy[0];
    }
}

// Kernel 3: score[b,s] = enc[b,s,:]·u + cov[b,s]*c + dscore[b]
// One wave per row; grid = B*S/4 = 8192 blocks, 256 threads (4 waves).
__global__ __launch_bounds__(256) void score_kernel(
    const float4* __restrict__ enc4, const float* __restrict__ cov,
    const float* __restrict__ ws, float* __restrict__ score) {
    int tid = threadIdx.x;
    int wave = tid >> 6, lane = tid & 63;
    int row = blockIdx.x * 4 + wave;          // [0, B*S)
    const float4* u4 = (const float4*)(ws + WS_U);
    float acc = 0.f;
    #pragma unroll
    for (int k = 0; k < 4; ++k) {
        float4 ev = enc4[(size_t)row * 256 + k * 64 + lane];
        float4 uv = u4[k * 64 + lane];
        acc += ev.x * uv.x + ev.y * uv.y + ev.z * uv.z + ev.w * uv.w;
    }
    acc = wave_reduce_sum(acc);
    if (lane == 0) {
        int b = row >> 10;
        score[row] = acc + cov[row] * ws[WS_C] + ws[WS_DS + b];
    }
}

// Kernel 4: masked softmax + renormalize; writes w and coverage_new to d_out.
// grid = 32 (one per b), block = 256.
__global__ __launch_bounds__(256) void softmax_kernel(
    const float* __restrict__ score, const float* __restrict__ mask,
    const float* __restrict__ cov, float* __restrict__ out) {
    int b = blockIdx.x, tid = threadIdx.x;
    __shared__ float red[256];
    float sc[4];
    #pragma unroll
    for (int k = 0; k < 4; ++k) sc[k] = score[b * S + tid + k * 256];
    float m = fmaxf(fmaxf(sc[0], sc[1]), fmaxf(sc[2], sc[3]));
    red[tid] = m; __syncthreads();
    for (int s = 128; s > 0; s >>= 1) {
        if (tid < s) red[tid] = fmaxf(red[tid], red[tid + s]);
        __syncthreads();
    }
    m = red[0];
    __syncthreads();
    float e[4]; float psum = 0.f;
    #pragma unroll
    for (int k = 0; k < 4; ++k) {
        int idx = b * S + tid + k * 256;
        e[k] = expf(sc[k] - m) * mask[idx];
        psum += e[k];
    }
    red[tid] = psum; __syncthreads();
    for (int s = 128; s > 0; s >>= 1) {
        if (tid < s) red[tid] += red[tid + s];
        __syncthreads();
    }
    float inv = 1.0f / red[0];
    #pragma unroll
    for (int k = 0; k < 4; ++k) {
        int idx = b * S + tid + k * 256;
        float w = e[k] * inv;
        out[B * D + idx] = w;                 // w output
        out[2 * B * D + idx] = cov[idx] + w;  // coverage_new output
    }
}

// Kernel 5: context partials over s-chunks of 64.
// grid = (schunk=16, b=32); block = 256 (each thread owns a float4 of d).
__global__ __launch_bounds__(256) void ctx_partial_kernel(
    const float4* __restrict__ enc4, const float* __restrict__ w,
    float4* __restrict__ part4) {
    int sc = blockIdx.x, b = blockIdx.y, tid = threadIdx.x;
    float4 acc = make_float4(0.f, 0.f, 0.f, 0.f);
    int s0 = sc * 64;
    #pragma unroll 4
    for (int i = 0; i < 64; ++i) {
        int s = s0 + i;
        float wv = w[b * S + s];
        float4 ev = enc4[((size_t)(b * S + s)) * 256 + tid];
        acc.x += wv * ev.x; acc.y += wv * ev.y;
        acc.z += wv * ev.z; acc.w += wv * ev.w;
    }
    part4[(size_t)(b * 16 + sc) * 256 + tid] = acc;
}

// Kernel 6: reduce 16 partials -> context in d_out[0 : B*D).
// grid = 32, block = 256.
__global__ __launch_bounds__(256) void ctx_reduce_kernel(
    const float4* __restrict__ part4, float4* __restrict__ out4) {
    int b = blockIdx.x, tid = threadIdx.x;
    float4 acc = make_float4(0.f, 0.f, 0.f, 0.f);
    #pragma unroll
    for (int sc = 0; sc < 16; ++sc) {
        float4 p = part4[(size_t)(b * 16 + sc) * 256 + tid];
        acc.x += p.x; acc.y += p.y; acc.z += p.z; acc.w += p.w;
    }
    out4[b * 256 + tid] = acc;
}

extern "C" void kernel_launch(void* const* d_in, const int* in_sizes, int n_in,
                              void* d_out, int out_size, void* d_ws, size_t ws_size,
                              hipStream_t stream) {
    const float* h_dec = (const float*)d_in[0];
    const float* c_dec = (const float*)d_in[1];
    const float* enc   = (const float*)d_in[2];
    const float* mask  = (const float*)d_in[3];
    const float* cov   = (const float*)d_in[4];
    const float* Wh    = (const float*)d_in[5];
    const float* Ws    = (const float*)d_in[6];
    const float* Wsb   = (const float*)d_in[7];
    const float* Wc    = (const float*)d_in[8];
    const float* v     = (const float*)d_in[9];
    float* out = (float*)d_out;
    float* ws  = (float*)d_ws;

    // zero the atomic-accumulated u/usw regions
    hipMemsetAsync(ws, 0, 2048 * sizeof(float), stream);

    prep_kernel<<<256, 256, 0, stream>>>(Wh, Ws, v, ws);
    dscore_kernel<<<32, 256, 0, stream>>>(h_dec, c_dec, Wsb, Wc, v, ws);
    score_kernel<<<B * S / 4, 256, 0, stream>>>((const float4*)enc, cov, ws, ws + WS_SCORE);
    softmax_kernel<<<B, 256, 0, stream>>>(ws + WS_SCORE, mask, cov, out);
    ctx_partial_kernel<<<dim3(16, B), 256, 0, stream>>>((const float4*)enc, out + B * D,
                                                        (float4*)(ws + WS_PART));
    ctx_reduce_kernel<<<B, 256, 0, stream>>>((const float4*)(ws + WS_PART), (float4*)out);
}

// Round 2
// 43.960 us; speedup vs baseline: 1.4131x; 1.4131x over previous
//
#include <hip/hip_runtime.h>
#include <math.h>

// Problem constants (B=32, S=1024, H=512, D=2H=1024)
#define B 32
#define S 1024
#define D 1024
#define H 512
#define NCHUNK 32            // s-chunks per batch
#define CROWS (S / NCHUNK)   // 32 rows per chunk
#define WROWS (CROWS / 4)    // 8 rows per wave

// Workspace layout (floats):
//   [0,1024)     u[d]   = sum_e v[e]*Wh_w[e,d]   (atomic accum)
//   [1024,2048)  usw[d] = sum_e v[e]*Ws_w[e,d]   (atomic accum)
//   [4096,36864) score[b*S+s]
//   ctx partials: (b,chunk,d)  ; ml partials: (b,chunk,{m,l})
#define WS_U      0
#define WS_USW    1024
#define WS_SCORE  4096
#define WS_CTX    (4096 + B * S)
#define WS_ML     (WS_CTX + B * NCHUNK * D)

__device__ inline float wave_reduce_sum(float v) {
    #pragma unroll
    for (int off = 32; off > 0; off >>= 1) v += __shfl_xor(v, off, 64);
    return v;
}

// Kernel 1: u[d] and usw[d] via e-split partial dots + atomicAdd.
// grid = 256 blocks: mat(2) x dchunk(4) x echunk(32); block = 256 threads.
__global__ __launch_bounds__(256) void prep_kernel(
    const float* __restrict__ Wh, const float* __restrict__ Ws,
    const float* __restrict__ v, float* __restrict__ ws) {
    int blk = blockIdx.x;
    int mat = blk >> 7;
    int dchunk = (blk >> 5) & 3;
    int echunk = blk & 31;
    const float* W = mat ? Ws : Wh;
    float* dst = ws + (mat ? WS_USW : WS_U);
    int d = dchunk * 256 + threadIdx.x;
    int e0 = echunk * 32;
    float acc = 0.f;
    #pragma unroll 8
    for (int e = e0; e < e0 + 32; ++e)
        acc += v[e] * W[e * D + d];
    atomicAdd(&dst[d], acc);
}

// Kernel 2 (fused): single pass over encoder_output.
// grid = (NCHUNK, B), block = 256 (4 waves, each owns WROWS rows).
// Per row: score = enc·u + cov*c + dscore[b]; online-softmax accumulate
// ctx slice in registers. Emits per-chunk partial (m, l, ctx[D]).
__global__ __launch_bounds__(256) void fused_kernel(
    const float4* __restrict__ enc4, const float* __restrict__ cov,
    const float* __restrict__ mask,
    const float* __restrict__ h_dec, const float* __restrict__ c_dec,
    const float* __restrict__ Ws_b, const float* __restrict__ Wc,
    const float* __restrict__ v, float* __restrict__ ws) {
    int chunk = blockIdx.x, b = blockIdx.y;
    int tid = threadIdx.x, wave = tid >> 6, lane = tid & 63;

    __shared__ float red[512];
    __shared__ float lds_ctx[4][D];
    __shared__ float lds_ml[4][2];

    // Block prologue: dsb = s_t[b]·usw + v·Ws_b ;  c = v·Wc  (all from L2)
    {
        const float* usw = ws + WS_USW;
        float pa = 0.f, pb = 0.f;
        #pragma unroll
        for (int k = 0; k < 4; ++k) {
            int i = tid + k * 256;
            float st = (i < H) ? h_dec[b * H + i] : c_dec[b * H + (i - H)];
            pa += st * usw[i] + v[i] * Ws_b[i];
            pb += v[i] * Wc[i];
        }
        red[tid] = pa; red[256 + tid] = pb;
    }
    __syncthreads();
    for (int st = 128; st > 0; st >>= 1) {
        if (tid < st) { red[tid] += red[tid + st]; red[256 + tid] += red[256 + tid + st]; }
        __syncthreads();
    }
    float dsb = red[0], cscale = red[256];

    // u slice for this lane stays in registers for the whole kernel
    const float4* u4 = (const float4*)(ws + WS_U);
    float4 uv0 = u4[lane * 4 + 0], uv1 = u4[lane * 4 + 1];
    float4 uv2 = u4[lane * 4 + 2], uv3 = u4[lane * 4 + 3];

    float m = -INFINITY, l = 0.f;
    float4 c0 = make_float4(0, 0, 0, 0), c1 = c0, c2 = c0, c3 = c0;

    int s_base = chunk * CROWS + wave * WROWS;
    for (int r = 0; r < WROWS; ++r) {
        int srow = s_base + r;
        int idx = b * S + srow;
        size_t rowoff = (size_t)idx * 256 + lane * 4;
        float4 e0 = enc4[rowoff + 0], e1 = enc4[rowoff + 1];
        float4 e2 = enc4[rowoff + 2], e3 = enc4[rowoff + 3];
        float acc = e0.x * uv0.x + e0.y * uv0.y + e0.z * uv0.z + e0.w * uv0.w
                  + e1.x * uv1.x + e1.y * uv1.y + e1.z * uv1.z + e1.w * uv1.w
                  + e2.x * uv2.x + e2.y * uv2.y + e2.z * uv2.z + e2.w * uv2.w
                  + e3.x * uv3.x + e3.y * uv3.y + e3.z * uv3.z + e3.w * uv3.w;
        acc = wave_reduce_sum(acc);
        float sc = acc + cov[idx] * cscale + dsb;
        if (lane == 0) ws[WS_SCORE + idx] = sc;
        if (sc > m) {                      // wave-uniform branch
            float scl = expf(m - sc);      // m=-inf first iter -> 0
            l *= scl;
            c0.x *= scl; c0.y *= scl; c0.z *= scl; c0.w *= scl;
            c1.x *= scl; c1.y *= scl; c1.z *= scl; c1.w *= scl;
            c2.x *= scl; c2.y *= scl; c2.z *= scl; c2.w *= scl;
            c3.x *= scl; c3.y *= scl; c3.z *= scl; c3.w *= scl;
            m = sc;
        }
        float e = expf(sc - m) * mask[idx];
        l += e;
        c0.x += e * e0.x; c0.y += e * e0.y; c0.z += e * e0.z; c0.w += e * e0.w;
        c1.x += e * e1.x; c1.y += e * e1.y; c1.z += e * e1.z; c1.w += e * e1.w;
        c2.x += e * e2.x; c2.y += e * e2.y; c2.z += e * e2.z; c2.w += e * e2.w;
        c3.x += e * e3.x; c3.y += e * e3.y; c3.z += e * e3.z; c3.w += e * e3.w;
    }

    // Cross-wave combine via LDS
    {
        float4* lc = (float4*)lds_ctx[wave];
        lc[lane * 4 + 0] = c0; lc[lane * 4 + 1] = c1;
        lc[lane * 4 + 2] = c2; lc[lane * 4 + 3] = c3;
        if (lane == 0) { lds_ml[wave][0] = m; lds_ml[wave][1] = l; }
    }
    __syncthreads();
    {
        float m0 = lds_ml[0][0], m1 = lds_ml[1][0], m2 = lds_ml[2][0], m3 = lds_ml[3][0];
        float mc = fmaxf(fmaxf(m0, m1), fmaxf(m2, m3));
        float f0 = expf(m0 - mc), f1 = expf(m1 - mc), f2 = expf(m2 - mc), f3 = expf(m3 - mc);
        float lc = lds_ml[0][1] * f0 + lds_ml[1][1] * f1 + lds_ml[2][1] * f2 + lds_ml[3][1] * f3;
        float4 t0 = ((float4*)lds_ctx[0])[tid];
        float4 t1 = ((float4*)lds_ctx[1])[tid];
        float4 t2 = ((float4*)lds_ctx[2])[tid];
        float4 t3 = ((float4*)lds_ctx[3])[tid];
        float4 a;
        a.x = f0 * t0.x + f1 * t1.x + f2 * t2.x + f3 * t3.x;
        a.y = f0 * t0.y + f1 * t1.y + f2 * t2.y + f3 * t3.y;
        a.z = f0 * t0.z + f1 * t1.z + f2 * t2.z + f3 * t3.z;
        a.w = f0 * t0.w + f1 * t1.w + f2 * t2.w + f3 * t3.w;
        ((float4*)(ws + WS_CTX))[(b * NCHUNK + chunk) * 256 + tid] = a;
        if (tid == 0) {
            ws[WS_ML + (b * NCHUNK + chunk) * 2 + 0] = mc;
            ws[WS_ML + (b * NCHUNK + chunk) * 2 + 1] = lc;
        }
    }
}

// Kernel 3: finalize. grid = (5, B).
// x<4: combine ctx partials for 256 d's each. x==4: write w and coverage_new.
__global__ __launch_bounds__(256) void finalize_kernel(
    const float* __restrict__ mask, const float* __restrict__ cov,
    const float* __restrict__ ws, float* __restrict__ out) {
    int part = blockIdx.x, b = blockIdx.y, tid = threadIdx.x;
    const float* ml = ws + WS_ML + b * NCHUNK * 2;
    float m_g = -INFINITY;
    #pragma unroll 8
    for (int c = 0; c < NCHUNK; ++c) m_g = fmaxf(m_g, ml[2 * c]);
    float l_g = 0.f;
    #pragma unroll 8
    for (int c = 0; c < NCHUNK; ++c) l_g += expf(ml[2 * c] - m_g) * ml[2 * c + 1];
    float inv = 1.0f / l_g;

    if (part < 4) {
        int d = part * 256 + tid;
        float a = 0.f;
        #pragma unroll 8
        for (int c = 0; c < NCHUNK; ++c)
            a += expf(ml[2 * c] - m_g) * ws[WS_CTX + (size_t)(b * NCHUNK + c) * D + d];
        out[b * D + d] = a * inv;
    } else {
        #pragma unroll
        for (int k = 0; k < 4; ++k) {
            int idx = b * S + tid + k * 256;
            float w = expf(ws[WS_SCORE + idx] - m_g) * mask[idx] * inv;
            out[B * D + idx] = w;                  // attention weights
            out[2 * B * D + idx] = cov[idx] + w;   // coverage_new
        }
    }
}

extern "C" void kernel_launch(void* const* d_in, const int* in_sizes, int n_in,
                              void* d_out, int out_size, void* d_ws, size_t ws_size,
                              hipStream_t stream) {
    const float* h_dec = (const float*)d_in[0];
    const float* c_dec = (const float*)d_in[1];
    const float* enc   = (const float*)d_in[2];
    const float* mask  = (const float*)d_in[3];
    const float* cov   = (const float*)d_in[4];
    const float* Wh    = (const float*)d_in[5];
    const float* Ws    = (const float*)d_in[6];
    const float* Wsb   = (const float*)d_in[7];
    const float* Wc    = (const float*)d_in[8];
    const float* v     = (const float*)d_in[9];
    float* out = (float*)d_out;
    float* ws  = (float*)d_ws;

    // zero the atomic-accumulated u/usw regions
    hipMemsetAsync(ws, 0, 2048 * sizeof(float), stream);

    prep_kernel<<<256, 256, 0, stream>>>(Wh, Ws, v, ws);
    fused_kernel<<<dim3(NCHUNK, B), 256, 0, stream>>>(
        (const float4*)enc, cov, mask, h_dec, c_dec, Wsb, Wc, v, ws);
    finalize_kernel<<<dim3(5, B), 256, 0, stream>>>(mask, cov, ws, out);
}